// Round 4
// baseline (1290.490 us; speedup 1.0000x reference)
//
#include <hip/hip_runtime.h>
#include <math.h>

// GCN 2-layer, N nodes, E edges, 64 -> 64 -> 32 channels.
// R4: no scattered global writes/atomics anywhere.
//  binA: chunk-local LDS counting sort by 128-node bucket, coalesced output.
//  bscan/compact: bucket-contiguous edge lists (packed (dl<<17)|src), per-node
//  degree via LDS atomics (fused dinv).
//  b1: per-bucket LDS accumulator + ds_add_f32 edge aggregation + fused gemm2.
//  b2: same for layer 2 + fused mean-pool.

#define C1 64
#define C2 32
#define CHUNK 8192
#define BNODES 128

__device__ __forceinline__ unsigned short f2bf(float f) {
    unsigned u = __float_as_uint(f);
    u = (u + 0x7FFFu + ((u >> 16) & 1u)) >> 16;
    return (unsigned short)u;
}
__device__ __forceinline__ float bf2f(unsigned short u) {
    return __uint_as_float((unsigned)u << 16);
}

// ---- binA: per-chunk LDS counting sort by bucket (dst>>7). Coalesced IO. ----
__global__ __launch_bounds__(256) void binA_kernel(
    const int* __restrict__ src, const int* __restrict__ dst, int E, int NB, int NC,
    unsigned* __restrict__ binned, int* __restrict__ startsT,
    int* __restrict__ countsT, unsigned* __restrict__ btot) {
    __shared__ unsigned hist[1024];
    __shared__ unsigned scan[1024];
    __shared__ unsigned part[256];
    __shared__ unsigned stage[CHUNK];
    int t = threadIdx.x;
    int c = blockIdx.x;
    int e0 = c * CHUNK;
    int len = min(CHUNK, E - e0);
    for (int i = t; i < 1024; i += 256) hist[i] = 0;
    __syncthreads();
    for (int i = t; i < len; i += 256)
        atomicAdd(&hist[dst[e0 + i] >> 7], 1u);
    __syncthreads();
    // exclusive scan of 1024 hist entries (4 per thread + block scan)
    unsigned v0 = hist[4 * t], v1 = hist[4 * t + 1], v2 = hist[4 * t + 2], v3 = hist[4 * t + 3];
    unsigned sum = v0 + v1 + v2 + v3;
    part[t] = sum;
    __syncthreads();
    for (int st = 1; st < 256; st <<= 1) {
        unsigned a = part[t];
        unsigned bl = (t >= st) ? part[t - st] : 0u;
        __syncthreads();
        part[t] = a + bl;
        __syncthreads();
    }
    unsigned base = part[t] - sum;
    scan[4 * t]     = base;
    scan[4 * t + 1] = base + v0;
    scan[4 * t + 2] = base + v0 + v1;
    scan[4 * t + 3] = base + v0 + v1 + v2;
    __syncthreads();
    for (int b = t; b < NB; b += 256) {
        unsigned cnt = hist[b];
        countsT[b * NC + c] = (int)cnt;
        startsT[b * NC + c] = e0 + (int)scan[b];
        if (cnt) atomicAdd(&btot[b], cnt);
    }
    // placement: scan[] doubles as LDS cursor
    for (int i = t; i < len; i += 256) {
        int s = src[e0 + i];
        int d = dst[e0 + i];
        unsigned pos = atomicAdd(&scan[d >> 7], 1u);
        stage[pos] = ((unsigned)(d & 127) << 17) | (unsigned)s;
    }
    __syncthreads();
    for (int i = t; i < len; i += 256) binned[e0 + i] = stage[i];
}

// ---- bscan: exclusive scan of per-bucket totals -> bstart[NB+1] ----
__global__ __launch_bounds__(256) void bscan_kernel(const unsigned* __restrict__ btot,
                                                    int* __restrict__ bstart, int NB) {
    __shared__ unsigned part[256];
    int t = threadIdx.x;
    unsigned v[4];
    unsigned sum = 0;
    for (int i = 0; i < 4; ++i) {
        int idx = 4 * t + i;
        v[i] = (idx < NB) ? btot[idx] : 0u;
        sum += v[i];
    }
    part[t] = sum;
    __syncthreads();
    for (int st = 1; st < 256; st <<= 1) {
        unsigned a = part[t];
        unsigned bl = (t >= st) ? part[t - st] : 0u;
        __syncthreads();
        part[t] = a + bl;
        __syncthreads();
    }
    unsigned run = part[t] - sum;
    for (int i = 0; i < 4; ++i) {
        int idx = 4 * t + i;
        if (idx < NB) bstart[idx] = (int)run;
        run += v[i];
    }
    if (t == 255) bstart[NB] = (int)run;
}

// ---- compact: gather chunk-segments into bucket-contiguous ebkt; fused deg->dinv ----
__global__ __launch_bounds__(256) void compact_kernel(
    const unsigned* __restrict__ binned, const int* __restrict__ startsT,
    const int* __restrict__ countsT, const int* __restrict__ bstart,
    int N, int NC, unsigned* __restrict__ ebkt, float* __restrict__ dinv) {
    __shared__ int sS[256], sC[256];
    __shared__ unsigned cur;
    __shared__ unsigned cnt[BNODES];
    int t = threadIdx.x;
    int b = blockIdx.x;
    if (t < NC) { sS[t] = startsT[b * NC + t]; sC[t] = countsT[b * NC + t]; }
    if (t == 0) cur = 0;
    if (t < BNODES) cnt[t] = 0;
    __syncthreads();
    int lane = t & 63, w = t >> 6;
    int dbase = bstart[b];
    for (int c = w; c < NC; c += 4) {
        int s0 = sS[c], len = sC[c];
        if (!len) continue;
        unsigned wb;
        if (lane == 0) wb = atomicAdd(&cur, (unsigned)len);
        wb = __shfl(wb, 0);
        for (int o = lane; o < len; o += 64) {
            unsigned ent = binned[s0 + o];
            atomicAdd(&cnt[ent >> 17], 1u);
            ebkt[dbase + (int)wb + o] = ent;
        }
    }
    __syncthreads();
    if (t < BNODES) {
        int n = b * BNODES + t;
        if (n < N) dinv[n] = rsqrtf((float)cnt[t] + 1.0f);
    }
}

// ---- gemm1: xws = bf16(dinv * (x @ W1)), one wave per row ----
__global__ __launch_bounds__(256) void gemm1_kernel(
    const float* __restrict__ x, const float* __restrict__ W,
    const float* __restrict__ dinv, unsigned short* __restrict__ xws, int N) {
    __shared__ __align__(16) float wt[64 * 68];
    for (int t = threadIdx.x; t < 64 * 64; t += blockDim.x) {
        int k = t >> 6, c = t & 63;
        wt[c * 68 + k] = W[t];
    }
    __syncthreads();
    int lane = threadIdx.x & 63;
    int wave = (blockIdx.x * blockDim.x + threadIdx.x) >> 6;
    int nw = (gridDim.x * blockDim.x) >> 6;
    const float4* wt4 = (const float4*)(wt + lane * 68);
    for (int n = wave; n < N; n += nw) {
        const float4* xr = (const float4*)(x + (size_t)n * C1);
        float acc = 0.f;
#pragma unroll
        for (int j = 0; j < 16; ++j) {
            float4 xx = xr[j];
            float4 ww = wt4[j];
            acc += xx.x * ww.x + xx.y * ww.y + xx.z * ww.z + xx.w * ww.w;
        }
        xws[(size_t)n * C1 + lane] = f2bf(dinv[n] * acc);
    }
}

// ---- b1: LDS acc aggregation (layer1) + fused gemm2 -> hws bf16 ----
// Block = 128-node bucket. acc stride 65 (bank-conflict-free epilogue).
__global__ __launch_bounds__(256) void b1_kernel(
    const ushort2* __restrict__ xws2, const unsigned* __restrict__ ebkt,
    const int* __restrict__ bstart, const float* __restrict__ dinv,
    const float* __restrict__ W2, const float* __restrict__ b1,
    unsigned short* __restrict__ hws, int N) {
    __shared__ float acc[BNODES * 65];
    __shared__ float w2s[64 * 32];
    __shared__ float b1s[64];
    __shared__ float dis[BNODES];
    int t = threadIdx.x;
    int b = blockIdx.x;
    int nbase = b * BNODES;
    int nloc = min(BNODES, N - nbase);
    for (int i = t; i < 64 * 32; i += 256) w2s[i] = W2[i];
    if (t < 64) b1s[t] = b1[t];
    if (t < BNODES) dis[t] = (t < nloc) ? dinv[nbase + t] : 0.f;
    __syncthreads();
    // init acc with self-loop term dinv[n]*xws[n]
    for (int i = t; i < BNODES * 32; i += 256) {
        int r = i >> 5, k2 = i & 31;
        float vx = 0.f, vy = 0.f;
        if (r < nloc) {
            ushort2 u = xws2[(size_t)(nbase + r) * 32 + k2];
            vx = dis[r] * bf2f(u.x);
            vy = dis[r] * bf2f(u.y);
        }
        acc[r * 65 + 2 * k2]     = vx;
        acc[r * 65 + 2 * k2 + 1] = vy;
    }
    __syncthreads();
    int k0g = bstart[b], kEnd = bstart[b + 1];
    int lane = t & 63, w = t >> 6;
    int c2 = lane & 31;
    for (int k0 = k0g + w * 32; k0 < kEnd; k0 += 128) {
        int li = k0 + c2;
        unsigned ent = (li < kEnd) ? ebkt[li] : 0u;
        int rem = kEnd - k0;
#pragma unroll
        for (int j = 0; j < 16; ++j) {
            int kk = 2 * j + (lane >> 5);
            unsigned e = __shfl(ent, kk);
            if (kk < rem) {
                ushort2 v = xws2[(size_t)(e & 0x1FFFFu) * 32 + c2];
                unsigned dl = e >> 17;
                atomicAdd(&acc[dl * 65 + 2 * c2],     bf2f(v.x));
                atomicAdd(&acc[dl * 65 + 2 * c2 + 1], bf2f(v.y));
            }
        }
    }
    __syncthreads();
    // fused gemm2: h = relu(dinv*acc + b1); hws = bf16(dinv * (h @ W2))
    int r = t & 127, cg = t >> 7;  // col group of 16
    if (r < nloc) {
        float di = dis[r];
        float o[16];
#pragma unroll
        for (int j = 0; j < 16; ++j) o[j] = 0.f;
        const float* arow = acc + r * 65;
        for (int k = 0; k < 64; ++k) {
            float h = fmaxf(di * arow[k] + b1s[k], 0.f);
            const float4* wr = (const float4*)(w2s + k * 32 + cg * 16);
            float4 wa = wr[0], wb = wr[1], wc = wr[2], wd = wr[3];
            o[0]  += h * wa.x; o[1]  += h * wa.y; o[2]  += h * wa.z; o[3]  += h * wa.w;
            o[4]  += h * wb.x; o[5]  += h * wb.y; o[6]  += h * wb.z; o[7]  += h * wb.w;
            o[8]  += h * wc.x; o[9]  += h * wc.y; o[10] += h * wc.z; o[11] += h * wc.w;
            o[12] += h * wd.x; o[13] += h * wd.y; o[14] += h * wd.z; o[15] += h * wd.w;
        }
        unsigned* hw = (unsigned*)(hws + (size_t)(nbase + r) * C2 + cg * 16);
#pragma unroll
        for (int j = 0; j < 8; ++j) {
            unsigned lo = f2bf(di * o[2 * j]);
            unsigned hi = f2bf(di * o[2 * j + 1]);
            hw[j] = lo | (hi << 16);
        }
    }
}

// ---- b2: LDS acc aggregation (layer2) + fused mean-pool ----
__global__ __launch_bounds__(256) void b2_kernel(
    const ushort2* __restrict__ hws2, const unsigned* __restrict__ ebkt,
    const int* __restrict__ bstart, const float* __restrict__ dinv,
    float* __restrict__ pooled, int N) {
    __shared__ float acc[BNODES * 33];
    __shared__ float dis[BNODES];
    __shared__ float red[8][32];
    int t = threadIdx.x;
    int b = blockIdx.x;
    int nbase = b * BNODES;
    int nloc = min(BNODES, N - nbase);
    if (t < BNODES) dis[t] = (t < nloc) ? dinv[nbase + t] : 0.f;
    __syncthreads();
    for (int i = t; i < BNODES * 16; i += 256) {
        int r = i >> 4, k2 = i & 15;
        float vx = 0.f, vy = 0.f;
        if (r < nloc) {
            ushort2 u = hws2[(size_t)(nbase + r) * 16 + k2];
            vx = dis[r] * bf2f(u.x);
            vy = dis[r] * bf2f(u.y);
        }
        acc[r * 33 + 2 * k2]     = vx;
        acc[r * 33 + 2 * k2 + 1] = vy;
    }
    __syncthreads();
    int k0g = bstart[b], kEnd = bstart[b + 1];
    int lane = t & 63, w = t >> 6;
    int c2 = lane & 15;
    for (int k0 = k0g + w * 64; k0 < kEnd; k0 += 256) {
        int li = k0 + lane;
        unsigned ent = (li < kEnd) ? ebkt[li] : 0u;
        int rem = kEnd - k0;
#pragma unroll
        for (int j = 0; j < 16; ++j) {
            int kk = 4 * j + (lane >> 4);
            unsigned e = __shfl(ent, kk);
            if (kk < rem) {
                ushort2 v = hws2[(size_t)(e & 0x1FFFFu) * 16 + c2];
                unsigned dl = e >> 17;
                atomicAdd(&acc[dl * 33 + 2 * c2],     bf2f(v.x));
                atomicAdd(&acc[dl * 33 + 2 * c2 + 1], bf2f(v.y));
            }
        }
    }
    __syncthreads();
    int c = t & 31, rg = t >> 5;
    float p = 0.f;
    for (int r = rg; r < nloc; r += 8) p += dis[r] * acc[r * 33 + c];
    red[rg][c] = p;
    __syncthreads();
    if (t < 32) {
        float s = 0.f;
#pragma unroll
        for (int g = 0; g < 8; ++g) s += red[g][t];
        atomicAdd(&pooled[t], s);
    }
}

// ---- final: mean + b2, log_softmax over 32 classes ----
__global__ void final_kernel(const float* __restrict__ pooled,
                             const float* __restrict__ b2, int N,
                             float* __restrict__ out) {
    int c = threadIdx.x & 31;
    float v = pooled[c] / (float)N + b2[c];
    float m = v;
    for (int off = 16; off; off >>= 1) m = fmaxf(m, __shfl_xor(m, off));
    float s = __expf(v - m);
    for (int off = 16; off; off >>= 1) s += __shfl_xor(s, off);
    if (threadIdx.x < 32) out[c] = v - m - logf(s);
}

extern "C" void kernel_launch(void* const* d_in, const int* in_sizes, int n_in,
                              void* d_out, int out_size, void* d_ws, size_t ws_size,
                              hipStream_t stream) {
    const float* x  = (const float*)d_in[0];
    const int*   ei = (const int*)d_in[1];
    const float* W1 = (const float*)d_in[2];
    const float* b1 = (const float*)d_in[3];
    const float* W2 = (const float*)d_in[4];
    const float* b2 = (const float*)d_in[5];
    float* out = (float*)d_out;

    int N = in_sizes[0] / C1;
    int E = in_sizes[1] / 2;
    const int* src = ei;
    const int* dst = ei + E;
    int NB = (N + BNODES - 1) / BNODES;   // 782
    int NC = (E + CHUNK - 1) / CHUNK;     // 196 (<= 256)

    char* ws = (char*)d_ws;
    size_t o = 0;
    auto alloc = [&](size_t bytes) { void* p = ws + o; o = (o + bytes + 255) & ~(size_t)255; return p; };
    unsigned*       btot    = (unsigned*)alloc((size_t)(NB + 1) * 4);
    int*            bstart  = (int*)alloc((size_t)(NB + 1) * 4);
    int*            startsT = (int*)alloc((size_t)NB * NC * 4);
    int*            countsT = (int*)alloc((size_t)NB * NC * 4);
    float*          dinv    = (float*)alloc((size_t)N * 4);
    float*          pooled  = (float*)alloc(32 * 4);
    unsigned*       binned  = (unsigned*)alloc((size_t)E * 4);
    unsigned*       ebkt    = (unsigned*)alloc((size_t)E * 4);
    unsigned short* xws     = (unsigned short*)alloc((size_t)N * C1 * 2);
    unsigned short* hws     = (unsigned short*)alloc((size_t)N * C2 * 2);

    hipMemsetAsync(btot, 0, (size_t)(NB + 1) * 4, stream);
    hipMemsetAsync(pooled, 0, 32 * 4, stream);

    binA_kernel<<<NC, 256, 0, stream>>>(src, dst, E, NB, NC, binned, startsT, countsT, btot);
    bscan_kernel<<<1, 256, 0, stream>>>(btot, bstart, NB);
    compact_kernel<<<NB, 256, 0, stream>>>(binned, startsT, countsT, bstart, N, NC, ebkt, dinv);
    gemm1_kernel<<<1024, 256, 0, stream>>>(x, W1, dinv, xws, N);
    b1_kernel<<<NB, 256, 0, stream>>>((const ushort2*)xws, ebkt, bstart, dinv, W2, b1, hws, N);
    b2_kernel<<<NB, 256, 0, stream>>>((const ushort2*)hws, ebkt, bstart, dinv, pooled, N);
    final_kernel<<<1, 64, 0, stream>>>(pooled, b2, N, out);
}

// Round 5
// 391.155 us; speedup vs baseline: 3.2992x; 3.2992x over previous
//
#include <hip/hip_runtime.h>
#include <math.h>

// GCN 2-layer, N nodes, E edges, 64 -> 64 -> 32 channels.
// R5: R4's coalesced chunk-sort front-end + R3's register-accumulating gathers.
//  binA: per-chunk LDS counting sort by 128-node bucket (packed (dl<<17)|src).
//  compact2: per-bucket per-node counting sort; scattered writes stay inside the
//  block's own 8KB output region (single-XCD lines, no bounce); fused deg->dinv.
//  gather1/gather2: half/quarter-wave per node, register accum, 8-wide unroll.

#define C1 64
#define C2 32
#define CHUNK 8192
#define BNODES 128

__device__ __forceinline__ unsigned short f2bf(float f) {
    unsigned u = __float_as_uint(f);
    u = (u + 0x7FFFu + ((u >> 16) & 1u)) >> 16;
    return (unsigned short)u;
}
__device__ __forceinline__ float bf2f(unsigned short u) {
    return __uint_as_float((unsigned)u << 16);
}

// ---- binA: per-chunk LDS counting sort by bucket (dst>>7). Coalesced IO. ----
__global__ __launch_bounds__(256) void binA_kernel(
    const int* __restrict__ src, const int* __restrict__ dst, int E, int NB, int NC,
    unsigned* __restrict__ binned, int* __restrict__ startsT,
    int* __restrict__ countsT, unsigned* __restrict__ btot) {
    __shared__ unsigned hist[1024];
    __shared__ unsigned scan[1024];
    __shared__ unsigned part[256];
    __shared__ unsigned stage[CHUNK];
    int t = threadIdx.x;
    int c = blockIdx.x;
    int e0 = c * CHUNK;
    int len = min(CHUNK, E - e0);
    for (int i = t; i < 1024; i += 256) hist[i] = 0;
    __syncthreads();
    for (int i = t; i < len; i += 256)
        atomicAdd(&hist[dst[e0 + i] >> 7], 1u);
    __syncthreads();
    unsigned v0 = hist[4 * t], v1 = hist[4 * t + 1], v2 = hist[4 * t + 2], v3 = hist[4 * t + 3];
    unsigned sum = v0 + v1 + v2 + v3;
    part[t] = sum;
    __syncthreads();
    for (int st = 1; st < 256; st <<= 1) {
        unsigned a = part[t];
        unsigned bl = (t >= st) ? part[t - st] : 0u;
        __syncthreads();
        part[t] = a + bl;
        __syncthreads();
    }
    unsigned base = part[t] - sum;
    scan[4 * t]     = base;
    scan[4 * t + 1] = base + v0;
    scan[4 * t + 2] = base + v0 + v1;
    scan[4 * t + 3] = base + v0 + v1 + v2;
    __syncthreads();
    for (int b = t; b < NB; b += 256) {
        unsigned cnt = hist[b];
        countsT[b * NC + c] = (int)cnt;
        startsT[b * NC + c] = e0 + (int)scan[b];
        if (cnt) atomicAdd(&btot[b], cnt);
    }
    for (int i = t; i < len; i += 256) {
        int s = src[e0 + i];
        int d = dst[e0 + i];
        unsigned pos = atomicAdd(&scan[d >> 7], 1u);
        stage[pos] = ((unsigned)(d & 127) << 17) | (unsigned)s;
    }
    __syncthreads();
    for (int i = t; i < len; i += 256) binned[e0 + i] = stage[i];
}

// ---- bscan: exclusive scan of per-bucket totals -> bstart[NB+1] ----
__global__ __launch_bounds__(256) void bscan_kernel(const unsigned* __restrict__ btot,
                                                    int* __restrict__ bstart, int NB) {
    __shared__ unsigned part[256];
    int t = threadIdx.x;
    unsigned v[4];
    unsigned sum = 0;
    for (int i = 0; i < 4; ++i) {
        int idx = 4 * t + i;
        v[i] = (idx < NB) ? btot[idx] : 0u;
        sum += v[i];
    }
    part[t] = sum;
    __syncthreads();
    for (int st = 1; st < 256; st <<= 1) {
        unsigned a = part[t];
        unsigned bl = (t >= st) ? part[t - st] : 0u;
        __syncthreads();
        part[t] = a + bl;
        __syncthreads();
    }
    unsigned run = part[t] - sum;
    for (int i = 0; i < 4; ++i) {
        int idx = 4 * t + i;
        if (idx < NB) bstart[idx] = (int)run;
        run += v[i];
    }
    if (t == 255) bstart[NB] = (int)run;
}

// ---- compact2: per-bucket per-node counting sort; fused deg->dinv + off ----
__global__ __launch_bounds__(256) void compact2_kernel(
    const unsigned* __restrict__ binned, const int* __restrict__ startsT,
    const int* __restrict__ countsT, const int* __restrict__ bstart,
    int N, int NC, int E, unsigned* __restrict__ ebkt, int* __restrict__ off,
    float* __restrict__ dinv) {
    __shared__ unsigned cnt[BNODES];
    __shared__ unsigned sc[BNODES];
    __shared__ unsigned cur[BNODES];
    __shared__ int sS[256], sC[256];
    int t = threadIdx.x;
    int b = blockIdx.x;
    if (t < BNODES) cnt[t] = 0;
    if (t < NC) { sS[t] = startsT[b * NC + t]; sC[t] = countsT[b * NC + t]; }
    __syncthreads();
    int lane = t & 63, w = t >> 6;
    // phase 1: per-node counts
    for (int c = w; c < NC; c += 4) {
        int s0 = sS[c], len = sC[c];
        for (int o = lane; o < len; o += 64)
            atomicAdd(&cnt[binned[s0 + o] >> 17], 1u);
    }
    __syncthreads();
    if (t < BNODES) sc[t] = cnt[t];
    __syncthreads();
    for (int st = 1; st < BNODES; st <<= 1) {
        unsigned v = 0;
        if (t < BNODES) { v = sc[t]; if (t >= st) v += sc[t - st]; }
        __syncthreads();
        if (t < BNODES) sc[t] = v;
        __syncthreads();
    }
    int dbase = bstart[b];
    if (t < BNODES) {
        unsigned excl = sc[t] - cnt[t];
        cur[t] = excl;
        int n = b * BNODES + t;
        if (n < N) {
            off[n] = dbase + (int)excl;
            dinv[n] = rsqrtf((float)cnt[t] + 1.0f);
        }
    }
    if (b == 0 && t == 0) off[N] = E;
    __syncthreads();
    // phase 2: place (scattered only within this block's own 8KB region)
    for (int c = w; c < NC; c += 4) {
        int s0 = sS[c], len = sC[c];
        for (int o = lane; o < len; o += 64) {
            unsigned ent = binned[s0 + o];
            unsigned pos = atomicAdd(&cur[ent >> 17], 1u);
            ebkt[dbase + (int)pos] = ent & 0x1FFFFu;
        }
    }
}

// ---- gemm1: xws = bf16(dinv * (x @ W1)), one wave per row ----
__global__ __launch_bounds__(256) void gemm1_kernel(
    const float* __restrict__ x, const float* __restrict__ W,
    const float* __restrict__ dinv, unsigned short* __restrict__ xws, int N) {
    __shared__ __align__(16) float wt[64 * 68];
    for (int t = threadIdx.x; t < 64 * 64; t += blockDim.x) {
        int k = t >> 6, c = t & 63;
        wt[c * 68 + k] = W[t];
    }
    __syncthreads();
    int lane = threadIdx.x & 63;
    int wave = (blockIdx.x * blockDim.x + threadIdx.x) >> 6;
    int nw = (gridDim.x * blockDim.x) >> 6;
    const float4* wt4 = (const float4*)(wt + lane * 68);
    for (int n = wave; n < N; n += nw) {
        const float4* xr = (const float4*)(x + (size_t)n * C1);
        float acc = 0.f;
#pragma unroll
        for (int j = 0; j < 16; ++j) {
            float4 xx = xr[j];
            float4 ww = wt4[j];
            acc += xx.x * ww.x + xx.y * ww.y + xx.z * ww.z + xx.w * ww.w;
        }
        xws[(size_t)n * C1 + lane] = f2bf(dinv[n] * acc);
    }
}

// ---- gather1: out1[n] = dinv[n]*(sum_e xws[src_e] + dinv[n]*xws[n]) ----
// Half-wave (32 lanes) per node, 2 channels per lane, 8-wide unroll.
__global__ __launch_bounds__(256) void gather1_kernel(
    const ushort2* __restrict__ xws2, const unsigned* __restrict__ ep,
    const int* __restrict__ off, const float* __restrict__ dinv,
    float2* __restrict__ out1, int N) {
    int lane = threadIdx.x & 63;
    int c2 = lane & 31;
    int slot = (((blockIdx.x * blockDim.x + threadIdx.x) >> 6) << 1) + (lane >> 5);
    int nslots = (gridDim.x * blockDim.x) >> 5;
    for (int n = slot; n < N; n += nslots) {
        float di = dinv[n];
        ushort2 sv = xws2[(size_t)n * 32 + c2];
        float a0 = di * bf2f(sv.x), a1 = di * bf2f(sv.y);
        int e = off[n], e1 = off[n + 1];
        for (; e + 7 < e1; e += 8) {
            unsigned s0 = ep[e],     s1 = ep[e + 1], s2 = ep[e + 2], s3 = ep[e + 3];
            unsigned s4 = ep[e + 4], s5 = ep[e + 5], s6 = ep[e + 6], s7 = ep[e + 7];
            ushort2 v0 = xws2[(size_t)s0 * 32 + c2];
            ushort2 v1 = xws2[(size_t)s1 * 32 + c2];
            ushort2 v2 = xws2[(size_t)s2 * 32 + c2];
            ushort2 v3 = xws2[(size_t)s3 * 32 + c2];
            ushort2 v4 = xws2[(size_t)s4 * 32 + c2];
            ushort2 v5 = xws2[(size_t)s5 * 32 + c2];
            ushort2 v6 = xws2[(size_t)s6 * 32 + c2];
            ushort2 v7 = xws2[(size_t)s7 * 32 + c2];
            a0 += bf2f(v0.x) + bf2f(v1.x) + bf2f(v2.x) + bf2f(v3.x)
                + bf2f(v4.x) + bf2f(v5.x) + bf2f(v6.x) + bf2f(v7.x);
            a1 += bf2f(v0.y) + bf2f(v1.y) + bf2f(v2.y) + bf2f(v3.y)
                + bf2f(v4.y) + bf2f(v5.y) + bf2f(v6.y) + bf2f(v7.y);
        }
        for (; e + 1 < e1; e += 2) {
            unsigned s0 = ep[e], s1 = ep[e + 1];
            ushort2 v0 = xws2[(size_t)s0 * 32 + c2];
            ushort2 v1 = xws2[(size_t)s1 * 32 + c2];
            a0 += bf2f(v0.x) + bf2f(v1.x);
            a1 += bf2f(v0.y) + bf2f(v1.y);
        }
        if (e < e1) {
            ushort2 v = xws2[(size_t)ep[e] * 32 + c2];
            a0 += bf2f(v.x);
            a1 += bf2f(v.y);
        }
        out1[(size_t)n * 32 + c2] = make_float2(di * a0, di * a1);
    }
}

// ---- gemm2: hws = bf16(dinv * (relu(out1 + b1) @ W2)), half-wave per row ----
__global__ __launch_bounds__(256) void gemm2_kernel(
    const float* __restrict__ out1, const float* __restrict__ W2,
    const float* __restrict__ b1, const float* __restrict__ dinv,
    unsigned short* __restrict__ hws, int N) {
    __shared__ __align__(16) float wt[32 * 68];
    __shared__ __align__(16) float b1s[64];
    for (int t = threadIdx.x; t < 64 * 32; t += blockDim.x) {
        int k = t >> 5, c = t & 31;
        wt[c * 68 + k] = W2[t];
    }
    if (threadIdx.x < 64) b1s[threadIdx.x] = b1[threadIdx.x];
    __syncthreads();
    int c = threadIdx.x & 31;
    int hwid = (blockIdx.x * blockDim.x + threadIdx.x) >> 5;
    int nh = (gridDim.x * blockDim.x) >> 5;
    const float4* wt4 = (const float4*)(wt + c * 68);
    const float4* b14 = (const float4*)b1s;
    for (int n = hwid; n < N; n += nh) {
        const float4* hr = (const float4*)(out1 + (size_t)n * C1);
        float acc = 0.f;
#pragma unroll
        for (int j = 0; j < 16; ++j) {
            float4 hh = hr[j];
            float4 bb = b14[j];
            float4 ww = wt4[j];
            float h0 = fmaxf(hh.x + bb.x, 0.f);
            float h1 = fmaxf(hh.y + bb.y, 0.f);
            float h2 = fmaxf(hh.z + bb.z, 0.f);
            float h3 = fmaxf(hh.w + bb.w, 0.f);
            acc += h0 * ww.x + h1 * ww.y + h2 * ww.z + h3 * ww.w;
        }
        hws[(size_t)n * C2 + c] = f2bf(dinv[n] * acc);
    }
}

// ---- gather2 + fused pool: quarter-wave per node, register accum ----
__global__ __launch_bounds__(256) void gather2_kernel(
    const ushort2* __restrict__ hws2, const unsigned* __restrict__ ep,
    const int* __restrict__ off, const float* __restrict__ dinv,
    float* __restrict__ pooled, int N) {
    __shared__ float ps[32];
    if (threadIdx.x < 32) ps[threadIdx.x] = 0.f;
    __syncthreads();
    int lane = threadIdx.x & 63;
    int c2 = lane & 15;
    int slot = (((blockIdx.x * blockDim.x + threadIdx.x) >> 6) << 2) + (lane >> 4);
    int nslots = (gridDim.x * blockDim.x) >> 4;
    float p0 = 0.f, p1 = 0.f;
    for (int n = slot; n < N; n += nslots) {
        float di = dinv[n];
        ushort2 sv = hws2[(size_t)n * 16 + c2];
        float a0 = di * bf2f(sv.x), a1 = di * bf2f(sv.y);
        int e = off[n], e1 = off[n + 1];
        for (; e + 7 < e1; e += 8) {
            unsigned s0 = ep[e],     s1 = ep[e + 1], s2 = ep[e + 2], s3 = ep[e + 3];
            unsigned s4 = ep[e + 4], s5 = ep[e + 5], s6 = ep[e + 6], s7 = ep[e + 7];
            ushort2 v0 = hws2[(size_t)s0 * 16 + c2];
            ushort2 v1 = hws2[(size_t)s1 * 16 + c2];
            ushort2 v2 = hws2[(size_t)s2 * 16 + c2];
            ushort2 v3 = hws2[(size_t)s3 * 16 + c2];
            ushort2 v4 = hws2[(size_t)s4 * 16 + c2];
            ushort2 v5 = hws2[(size_t)s5 * 16 + c2];
            ushort2 v6 = hws2[(size_t)s6 * 16 + c2];
            ushort2 v7 = hws2[(size_t)s7 * 16 + c2];
            a0 += bf2f(v0.x) + bf2f(v1.x) + bf2f(v2.x) + bf2f(v3.x)
                + bf2f(v4.x) + bf2f(v5.x) + bf2f(v6.x) + bf2f(v7.x);
            a1 += bf2f(v0.y) + bf2f(v1.y) + bf2f(v2.y) + bf2f(v3.y)
                + bf2f(v4.y) + bf2f(v5.y) + bf2f(v6.y) + bf2f(v7.y);
        }
        for (; e < e1; ++e) {
            ushort2 v = hws2[(size_t)ep[e] * 16 + c2];
            a0 += bf2f(v.x);
            a1 += bf2f(v.y);
        }
        p0 += di * a0;
        p1 += di * a1;
    }
    atomicAdd(&ps[2 * c2], p0);
    atomicAdd(&ps[2 * c2 + 1], p1);
    __syncthreads();
    if (threadIdx.x < 32) atomicAdd(&pooled[threadIdx.x], ps[threadIdx.x]);
}

// ---- final: mean + b2, log_softmax over 32 classes ----
__global__ void final_kernel(const float* __restrict__ pooled,
                             const float* __restrict__ b2, int N,
                             float* __restrict__ out) {
    int c = threadIdx.x & 31;
    float v = pooled[c] / (float)N + b2[c];
    float m = v;
    for (int off = 16; off; off >>= 1) m = fmaxf(m, __shfl_xor(m, off));
    float s = __expf(v - m);
    for (int off = 16; off; off >>= 1) s += __shfl_xor(s, off);
    if (threadIdx.x < 32) out[c] = v - m - logf(s);
}

extern "C" void kernel_launch(void* const* d_in, const int* in_sizes, int n_in,
                              void* d_out, int out_size, void* d_ws, size_t ws_size,
                              hipStream_t stream) {
    const float* x  = (const float*)d_in[0];
    const int*   ei = (const int*)d_in[1];
    const float* W1 = (const float*)d_in[2];
    const float* b1 = (const float*)d_in[3];
    const float* W2 = (const float*)d_in[4];
    const float* b2 = (const float*)d_in[5];
    float* out = (float*)d_out;

    int N = in_sizes[0] / C1;
    int E = in_sizes[1] / 2;
    const int* src = ei;
    const int* dst = ei + E;
    int NB = (N + BNODES - 1) / BNODES;   // 782
    int NC = (E + CHUNK - 1) / CHUNK;     // 196 (<= 256)

    char* ws = (char*)d_ws;
    size_t o = 0;
    auto alloc = [&](size_t bytes) { void* p = ws + o; o = (o + bytes + 255) & ~(size_t)255; return p; };
    unsigned*       btot    = (unsigned*)alloc((size_t)(NB + 1) * 4);
    int*            bstart  = (int*)alloc((size_t)(NB + 1) * 4);
    int*            startsT = (int*)alloc((size_t)NB * NC * 4);
    int*            countsT = (int*)alloc((size_t)NB * NC * 4);
    float*          dinv    = (float*)alloc((size_t)N * 4);
    int*            off     = (int*)alloc((size_t)(N + 1) * 4);
    float*          pooled  = (float*)alloc(32 * 4);
    unsigned*       binned  = (unsigned*)alloc((size_t)E * 4);
    unsigned*       ebkt    = (unsigned*)alloc((size_t)E * 4);
    unsigned short* xws     = (unsigned short*)alloc((size_t)N * C1 * 2);
    float*          out1    = (float*)alloc((size_t)N * C1 * 4);
    unsigned short* hws     = (unsigned short*)alloc((size_t)N * C2 * 2);

    hipMemsetAsync(btot, 0, (size_t)(NB + 1) * 4, stream);
    hipMemsetAsync(pooled, 0, 32 * 4, stream);

    binA_kernel<<<NC, 256, 0, stream>>>(src, dst, E, NB, NC, binned, startsT, countsT, btot);
    bscan_kernel<<<1, 256, 0, stream>>>(btot, bstart, NB);
    compact2_kernel<<<NB, 256, 0, stream>>>(binned, startsT, countsT, bstart, N, NC, E,
                                            ebkt, off, dinv);
    gemm1_kernel<<<1024, 256, 0, stream>>>(x, W1, dinv, xws, N);
    gather1_kernel<<<6144, 256, 0, stream>>>((const ushort2*)xws, ebkt, off, dinv,
                                             (float2*)out1, N);
    gemm2_kernel<<<1024, 256, 0, stream>>>(out1, W2, b1, dinv, hws, N);
    gather2_kernel<<<4096, 256, 0, stream>>>((const ushort2*)hws, ebkt, off, dinv,
                                             pooled, N);
    final_kernel<<<1, 64, 0, stream>>>(pooled, b2, N, out);
}

// Round 6
// 323.365 us; speedup vs baseline: 3.9908x; 1.2096x over previous
//
#include <hip/hip_runtime.h>
#include <math.h>

// GCN 2-layer, N nodes, E edges, 64 -> 64 -> 32 channels.
// R6: GEMMs restructured: W in VGPRs (lane = out channel), x rows staged into
// wave-private LDS via coalesced float4 (4 rows / 1KB instr), read back as
// same-address broadcast ds_read_b128 (conflict-free, 64x less LDS traffic).
// Front-end (binA/bscan/compact2) and gathers unchanged from R5.

#define C1 64
#define C2 32
#define CHUNK 8192
#define BNODES 128

__device__ __forceinline__ unsigned short f2bf(float f) {
    unsigned u = __float_as_uint(f);
    u = (u + 0x7FFFu + ((u >> 16) & 1u)) >> 16;
    return (unsigned short)u;
}
__device__ __forceinline__ float bf2f(unsigned short u) {
    return __uint_as_float((unsigned)u << 16);
}

// ---- binA: per-chunk LDS counting sort by bucket (dst>>7). Coalesced IO. ----
__global__ __launch_bounds__(256) void binA_kernel(
    const int* __restrict__ src, const int* __restrict__ dst, int E, int NB, int NC,
    unsigned* __restrict__ binned, int* __restrict__ startsT,
    int* __restrict__ countsT, unsigned* __restrict__ btot) {
    __shared__ unsigned hist[1024];
    __shared__ unsigned scan[1024];
    __shared__ unsigned part[256];
    __shared__ unsigned stage[CHUNK];
    int t = threadIdx.x;
    int c = blockIdx.x;
    int e0 = c * CHUNK;
    int len = min(CHUNK, E - e0);
    for (int i = t; i < 1024; i += 256) hist[i] = 0;
    __syncthreads();
    for (int i = t; i < len; i += 256)
        atomicAdd(&hist[dst[e0 + i] >> 7], 1u);
    __syncthreads();
    unsigned v0 = hist[4 * t], v1 = hist[4 * t + 1], v2 = hist[4 * t + 2], v3 = hist[4 * t + 3];
    unsigned sum = v0 + v1 + v2 + v3;
    part[t] = sum;
    __syncthreads();
    for (int st = 1; st < 256; st <<= 1) {
        unsigned a = part[t];
        unsigned bl = (t >= st) ? part[t - st] : 0u;
        __syncthreads();
        part[t] = a + bl;
        __syncthreads();
    }
    unsigned base = part[t] - sum;
    scan[4 * t]     = base;
    scan[4 * t + 1] = base + v0;
    scan[4 * t + 2] = base + v0 + v1;
    scan[4 * t + 3] = base + v0 + v1 + v2;
    __syncthreads();
    for (int b = t; b < NB; b += 256) {
        unsigned cnt = hist[b];
        countsT[b * NC + c] = (int)cnt;
        startsT[b * NC + c] = e0 + (int)scan[b];
        if (cnt) atomicAdd(&btot[b], cnt);
    }
    for (int i = t; i < len; i += 256) {
        int s = src[e0 + i];
        int d = dst[e0 + i];
        unsigned pos = atomicAdd(&scan[d >> 7], 1u);
        stage[pos] = ((unsigned)(d & 127) << 17) | (unsigned)s;
    }
    __syncthreads();
    for (int i = t; i < len; i += 256) binned[e0 + i] = stage[i];
}

// ---- bscan: exclusive scan of per-bucket totals -> bstart[NB+1] ----
__global__ __launch_bounds__(256) void bscan_kernel(const unsigned* __restrict__ btot,
                                                    int* __restrict__ bstart, int NB) {
    __shared__ unsigned part[256];
    int t = threadIdx.x;
    unsigned v[4];
    unsigned sum = 0;
    for (int i = 0; i < 4; ++i) {
        int idx = 4 * t + i;
        v[i] = (idx < NB) ? btot[idx] : 0u;
        sum += v[i];
    }
    part[t] = sum;
    __syncthreads();
    for (int st = 1; st < 256; st <<= 1) {
        unsigned a = part[t];
        unsigned bl = (t >= st) ? part[t - st] : 0u;
        __syncthreads();
        part[t] = a + bl;
        __syncthreads();
    }
    unsigned run = part[t] - sum;
    for (int i = 0; i < 4; ++i) {
        int idx = 4 * t + i;
        if (idx < NB) bstart[idx] = (int)run;
        run += v[i];
    }
    if (t == 255) bstart[NB] = (int)run;
}

// ---- compact2: per-bucket per-node counting sort; fused deg->dinv + off ----
__global__ __launch_bounds__(256) void compact2_kernel(
    const unsigned* __restrict__ binned, const int* __restrict__ startsT,
    const int* __restrict__ countsT, const int* __restrict__ bstart,
    int N, int NC, int E, unsigned* __restrict__ ebkt, int* __restrict__ off,
    float* __restrict__ dinv) {
    __shared__ unsigned cnt[BNODES];
    __shared__ unsigned sc[BNODES];
    __shared__ unsigned cur[BNODES];
    __shared__ int sS[256], sC[256];
    int t = threadIdx.x;
    int b = blockIdx.x;
    if (t < BNODES) cnt[t] = 0;
    if (t < NC) { sS[t] = startsT[b * NC + t]; sC[t] = countsT[b * NC + t]; }
    __syncthreads();
    int lane = t & 63, w = t >> 6;
    for (int c = w; c < NC; c += 4) {
        int s0 = sS[c], len = sC[c];
        for (int o = lane; o < len; o += 64)
            atomicAdd(&cnt[binned[s0 + o] >> 17], 1u);
    }
    __syncthreads();
    if (t < BNODES) sc[t] = cnt[t];
    __syncthreads();
    for (int st = 1; st < BNODES; st <<= 1) {
        unsigned v = 0;
        if (t < BNODES) { v = sc[t]; if (t >= st) v += sc[t - st]; }
        __syncthreads();
        if (t < BNODES) sc[t] = v;
        __syncthreads();
    }
    int dbase = bstart[b];
    if (t < BNODES) {
        unsigned excl = sc[t] - cnt[t];
        cur[t] = excl;
        int n = b * BNODES + t;
        if (n < N) {
            off[n] = dbase + (int)excl;
            dinv[n] = rsqrtf((float)cnt[t] + 1.0f);
        }
    }
    if (b == 0 && t == 0) off[N] = E;
    __syncthreads();
    for (int c = w; c < NC; c += 4) {
        int s0 = sS[c], len = sC[c];
        for (int o = lane; o < len; o += 64) {
            unsigned ent = binned[s0 + o];
            unsigned pos = atomicAdd(&cur[ent >> 17], 1u);
            ebkt[dbase + (int)pos] = ent & 0x1FFFFu;
        }
    }
}

// ---- gemm1: xws = bf16(dinv * (x @ W1)) ----
// Lane c holds W1[:,c] in 64 VGPRs. 4 rows staged per coalesced 1KB LDS write,
// read back via same-address broadcast ds_read_b128.
__global__ __launch_bounds__(256) void gemm1_kernel(
    const float* __restrict__ x, const float* __restrict__ W,
    const float* __restrict__ dinv, unsigned short* __restrict__ xws, int N) {
    __shared__ __align__(16) float stage[4][256];
    int t = threadIdx.x;
    int lane = t & 63;
    int w = t >> 6;
    float wv[64];
#pragma unroll
    for (int k = 0; k < 64; ++k) wv[k] = W[k * 64 + lane];
    float* buf = stage[w];
    int wave = (blockIdx.x * blockDim.x + t) >> 6;
    int nw = (gridDim.x * blockDim.x) >> 6;
    for (int g0 = wave * 4; g0 < N; g0 += nw * 4) {
        int nrem = N - g0;
        int nfl = min(nrem * 16, 64);
        const float4* xr = (const float4*)(x + (size_t)g0 * C1);
        float4 v = make_float4(0.f, 0.f, 0.f, 0.f);
        if (lane < nfl) v = xr[lane];
        ((float4*)buf)[lane] = v;  // wave-private; compiler inserts lgkm wait
        const float4* b0 = (const float4*)(buf);
        const float4* b1p = (const float4*)(buf + 64);
        const float4* b2p = (const float4*)(buf + 128);
        const float4* b3p = (const float4*)(buf + 192);
        float a0 = 0.f, a1 = 0.f, a2 = 0.f, a3 = 0.f;
#pragma unroll
        for (int j = 0; j < 16; ++j) {
            float4 x0 = b0[j], x1 = b1p[j], x2 = b2p[j], x3 = b3p[j];
            float w0 = wv[4 * j], w1 = wv[4 * j + 1], w2 = wv[4 * j + 2], w3 = wv[4 * j + 3];
            a0 += x0.x * w0 + x0.y * w1 + x0.z * w2 + x0.w * w3;
            a1 += x1.x * w0 + x1.y * w1 + x1.z * w2 + x1.w * w3;
            a2 += x2.x * w0 + x2.y * w1 + x2.z * w2 + x2.w * w3;
            a3 += x3.x * w0 + x3.y * w1 + x3.z * w2 + x3.w * w3;
        }
        xws[(size_t)g0 * C1 + lane] = f2bf(dinv[g0] * a0);
        if (nrem > 1) xws[(size_t)(g0 + 1) * C1 + lane] = f2bf(dinv[g0 + 1] * a1);
        if (nrem > 2) xws[(size_t)(g0 + 2) * C1 + lane] = f2bf(dinv[g0 + 2] * a2);
        if (nrem > 3) xws[(size_t)(g0 + 3) * C1 + lane] = f2bf(dinv[g0 + 3] * a3);
    }
}

// ---- gather1: out1[n] = dinv[n]*(sum_e xws[src_e] + dinv[n]*xws[n]) ----
__global__ __launch_bounds__(256) void gather1_kernel(
    const ushort2* __restrict__ xws2, const unsigned* __restrict__ ep,
    const int* __restrict__ off, const float* __restrict__ dinv,
    float2* __restrict__ out1, int N) {
    int lane = threadIdx.x & 63;
    int c2 = lane & 31;
    int slot = (((blockIdx.x * blockDim.x + threadIdx.x) >> 6) << 1) + (lane >> 5);
    int nslots = (gridDim.x * blockDim.x) >> 5;
    for (int n = slot; n < N; n += nslots) {
        float di = dinv[n];
        ushort2 sv = xws2[(size_t)n * 32 + c2];
        float a0 = di * bf2f(sv.x), a1 = di * bf2f(sv.y);
        int e = off[n], e1 = off[n + 1];
        for (; e + 7 < e1; e += 8) {
            unsigned s0 = ep[e],     s1 = ep[e + 1], s2 = ep[e + 2], s3 = ep[e + 3];
            unsigned s4 = ep[e + 4], s5 = ep[e + 5], s6 = ep[e + 6], s7 = ep[e + 7];
            ushort2 v0 = xws2[(size_t)s0 * 32 + c2];
            ushort2 v1 = xws2[(size_t)s1 * 32 + c2];
            ushort2 v2 = xws2[(size_t)s2 * 32 + c2];
            ushort2 v3 = xws2[(size_t)s3 * 32 + c2];
            ushort2 v4 = xws2[(size_t)s4 * 32 + c2];
            ushort2 v5 = xws2[(size_t)s5 * 32 + c2];
            ushort2 v6 = xws2[(size_t)s6 * 32 + c2];
            ushort2 v7 = xws2[(size_t)s7 * 32 + c2];
            a0 += bf2f(v0.x) + bf2f(v1.x) + bf2f(v2.x) + bf2f(v3.x)
                + bf2f(v4.x) + bf2f(v5.x) + bf2f(v6.x) + bf2f(v7.x);
            a1 += bf2f(v0.y) + bf2f(v1.y) + bf2f(v2.y) + bf2f(v3.y)
                + bf2f(v4.y) + bf2f(v5.y) + bf2f(v6.y) + bf2f(v7.y);
        }
        for (; e + 1 < e1; e += 2) {
            unsigned s0 = ep[e], s1 = ep[e + 1];
            ushort2 v0 = xws2[(size_t)s0 * 32 + c2];
            ushort2 v1 = xws2[(size_t)s1 * 32 + c2];
            a0 += bf2f(v0.x) + bf2f(v1.x);
            a1 += bf2f(v0.y) + bf2f(v1.y);
        }
        if (e < e1) {
            ushort2 v = xws2[(size_t)ep[e] * 32 + c2];
            a0 += bf2f(v.x);
            a1 += bf2f(v.y);
        }
        out1[(size_t)n * 32 + c2] = make_float2(di * a0, di * a1);
    }
}

// ---- gemm2: hws = bf16(dinv * (relu(out1 + b1) @ W2)) ----
// Lane (lane&31) holds W2[:,c] in 64 VGPRs. relu+bias applied at staging.
// Half-wave per row: half 0 -> rows 0,1 of the group, half 1 -> rows 2,3.
__global__ __launch_bounds__(256) void gemm2_kernel(
    const float* __restrict__ out1, const float* __restrict__ W2,
    const float* __restrict__ b1, const float* __restrict__ dinv,
    unsigned short* __restrict__ hws, int N) {
    __shared__ __align__(16) float stage[4][256];
    int t = threadIdx.x;
    int lane = t & 63;
    int w = t >> 6;
    int c = lane & 31;
    int half = lane >> 5;
    float wv[64];
#pragma unroll
    for (int k = 0; k < 64; ++k) wv[k] = W2[k * 32 + c];
    float4 bc = ((const float4*)b1)[lane & 15];
    float* buf = stage[w];
    int wave = (blockIdx.x * blockDim.x + t) >> 6;
    int nw = (gridDim.x * blockDim.x) >> 6;
    for (int g0 = wave * 4; g0 < N; g0 += nw * 4) {
        int nrem = N - g0;
        int nfl = min(nrem * 16, 64);
        const float4* xr = (const float4*)(out1 + (size_t)g0 * C1);
        float4 v = make_float4(0.f, 0.f, 0.f, 0.f);
        if (lane < nfl) v = xr[lane];
        v.x = fmaxf(v.x + bc.x, 0.f);
        v.y = fmaxf(v.y + bc.y, 0.f);
        v.z = fmaxf(v.z + bc.z, 0.f);
        v.w = fmaxf(v.w + bc.w, 0.f);
        ((float4*)buf)[lane] = v;
        int r0 = 2 * half;
        const float4* bx0 = (const float4*)(buf + r0 * 64);
        const float4* bx1 = (const float4*)(buf + (r0 + 1) * 64);
        float a0 = 0.f, a1 = 0.f;
#pragma unroll
        for (int j = 0; j < 16; ++j) {
            float4 x0 = bx0[j], x1 = bx1[j];
            float w0 = wv[4 * j], w1 = wv[4 * j + 1], w2 = wv[4 * j + 2], w3 = wv[4 * j + 3];
            a0 += x0.x * w0 + x0.y * w1 + x0.z * w2 + x0.w * w3;
            a1 += x1.x * w0 + x1.y * w1 + x1.z * w2 + x1.w * w3;
        }
        int n0 = g0 + r0;
        if (n0 < N)     hws[(size_t)n0 * C2 + c]       = f2bf(dinv[n0] * a0);
        if (n0 + 1 < N) hws[(size_t)(n0 + 1) * C2 + c] = f2bf(dinv[n0 + 1] * a1);
    }
}

// ---- gather2 + fused pool: quarter-wave per node, register accum ----
__global__ __launch_bounds__(256) void gather2_kernel(
    const ushort2* __restrict__ hws2, const unsigned* __restrict__ ep,
    const int* __restrict__ off, const float* __restrict__ dinv,
    float* __restrict__ pooled, int N) {
    __shared__ float ps[32];
    if (threadIdx.x < 32) ps[threadIdx.x] = 0.f;
    __syncthreads();
    int lane = threadIdx.x & 63;
    int c2 = lane & 15;
    int slot = (((blockIdx.x * blockDim.x + threadIdx.x) >> 6) << 2) + (lane >> 4);
    int nslots = (gridDim.x * blockDim.x) >> 4;
    float p0 = 0.f, p1 = 0.f;
    for (int n = slot; n < N; n += nslots) {
        float di = dinv[n];
        ushort2 sv = hws2[(size_t)n * 16 + c2];
        float a0 = di * bf2f(sv.x), a1 = di * bf2f(sv.y);
        int e = off[n], e1 = off[n + 1];
        for (; e + 7 < e1; e += 8) {
            unsigned s0 = ep[e],     s1 = ep[e + 1], s2 = ep[e + 2], s3 = ep[e + 3];
            unsigned s4 = ep[e + 4], s5 = ep[e + 5], s6 = ep[e + 6], s7 = ep[e + 7];
            ushort2 v0 = hws2[(size_t)s0 * 16 + c2];
            ushort2 v1 = hws2[(size_t)s1 * 16 + c2];
            ushort2 v2 = hws2[(size_t)s2 * 16 + c2];
            ushort2 v3 = hws2[(size_t)s3 * 16 + c2];
            ushort2 v4 = hws2[(size_t)s4 * 16 + c2];
            ushort2 v5 = hws2[(size_t)s5 * 16 + c2];
            ushort2 v6 = hws2[(size_t)s6 * 16 + c2];
            ushort2 v7 = hws2[(size_t)s7 * 16 + c2];
            a0 += bf2f(v0.x) + bf2f(v1.x) + bf2f(v2.x) + bf2f(v3.x)
                + bf2f(v4.x) + bf2f(v5.x) + bf2f(v6.x) + bf2f(v7.x);
            a1 += bf2f(v0.y) + bf2f(v1.y) + bf2f(v2.y) + bf2f(v3.y)
                + bf2f(v4.y) + bf2f(v5.y) + bf2f(v6.y) + bf2f(v7.y);
        }
        for (; e < e1; ++e) {
            ushort2 v = hws2[(size_t)ep[e] * 16 + c2];
            a0 += bf2f(v.x);
            a1 += bf2f(v.y);
        }
        p0 += di * a0;
        p1 += di * a1;
    }
    atomicAdd(&ps[2 * c2], p0);
    atomicAdd(&ps[2 * c2 + 1], p1);
    __syncthreads();
    if (threadIdx.x < 32) atomicAdd(&pooled[threadIdx.x], ps[threadIdx.x]);
}

// ---- final: mean + b2, log_softmax over 32 classes ----
__global__ void final_kernel(const float* __restrict__ pooled,
                             const float* __restrict__ b2, int N,
                             float* __restrict__ out) {
    int c = threadIdx.x & 31;
    float v = pooled[c] / (float)N + b2[c];
    float m = v;
    for (int off = 16; off; off >>= 1) m = fmaxf(m, __shfl_xor(m, off));
    float s = __expf(v - m);
    for (int off = 16; off; off >>= 1) s += __shfl_xor(s, off);
    if (threadIdx.x < 32) out[c] = v - m - logf(s);
}

extern "C" void kernel_launch(void* const* d_in, const int* in_sizes, int n_in,
                              void* d_out, int out_size, void* d_ws, size_t ws_size,
                              hipStream_t stream) {
    const float* x  = (const float*)d_in[0];
    const int*   ei = (const int*)d_in[1];
    const float* W1 = (const float*)d_in[2];
    const float* b1 = (const float*)d_in[3];
    const float* W2 = (const float*)d_in[4];
    const float* b2 = (const float*)d_in[5];
    float* out = (float*)d_out;

    int N = in_sizes[0] / C1;
    int E = in_sizes[1] / 2;
    const int* src = ei;
    const int* dst = ei + E;
    int NB = (N + BNODES - 1) / BNODES;   // 782
    int NC = (E + CHUNK - 1) / CHUNK;     // 196 (<= 256)

    char* ws = (char*)d_ws;
    size_t o = 0;
    auto alloc = [&](size_t bytes) { void* p = ws + o; o = (o + bytes + 255) & ~(size_t)255; return p; };
    unsigned*       btot    = (unsigned*)alloc((size_t)(NB + 1) * 4);
    int*            bstart  = (int*)alloc((size_t)(NB + 1) * 4);
    int*            startsT = (int*)alloc((size_t)NB * NC * 4);
    int*            countsT = (int*)alloc((size_t)NB * NC * 4);
    float*          dinv    = (float*)alloc((size_t)N * 4);
    int*            off     = (int*)alloc((size_t)(N + 1) * 4);
    float*          pooled  = (float*)alloc(32 * 4);
    unsigned*       binned  = (unsigned*)alloc((size_t)E * 4);
    unsigned*       ebkt    = (unsigned*)alloc((size_t)E * 4);
    unsigned short* xws     = (unsigned short*)alloc((size_t)N * C1 * 2);
    float*          out1    = (float*)alloc((size_t)N * C1 * 4);
    unsigned short* hws     = (unsigned short*)alloc((size_t)N * C2 * 2);

    hipMemsetAsync(btot, 0, (size_t)(NB + 1) * 4, stream);
    hipMemsetAsync(pooled, 0, 32 * 4, stream);

    binA_kernel<<<NC, 256, 0, stream>>>(src, dst, E, NB, NC, binned, startsT, countsT, btot);
    bscan_kernel<<<1, 256, 0, stream>>>(btot, bstart, NB);
    compact2_kernel<<<NB, 256, 0, stream>>>(binned, startsT, countsT, bstart, N, NC, E,
                                            ebkt, off, dinv);
    gemm1_kernel<<<1024, 256, 0, stream>>>(x, W1, dinv, xws, N);
    gather1_kernel<<<6144, 256, 0, stream>>>((const ushort2*)xws, ebkt, off, dinv,
                                             (float2*)out1, N);
    gemm2_kernel<<<1024, 256, 0, stream>>>(out1, W2, b1, dinv, hws, N);
    gather2_kernel<<<4096, 256, 0, stream>>>((const ushort2*)hws, ebkt, off, dinv,
                                             pooled, N);
    final_kernel<<<1, 64, 0, stream>>>(pooled, b2, N, out);
}